// Round 12
// baseline (208.763 us; speedup 1.0000x reference)
//
#include <hip/hip_runtime.h>
#include <math.h>

#define NB 8
#define NT 32
#define NAG 50
#define MTASK 100
#define MTOP 10
#define NNB 10
#define LDIM 5
#define HDIM 512
#define INDIM 1610
#define KP1 1664            // INDIM padded to multiple of 64
#define NKT1 (KP1/32)       // 52 k-chunks
#define NKT2 (HDIM/32)      // 16
#define NROWS (NB*NT*NAG)   // 12800
#define NOUT (MTOP+1)       // 11
#define PLANE ((size_t)NROWS * HDIM)

typedef float f32x4 __attribute__((ext_vector_type(4)));
typedef __bf16 bf16x8 __attribute__((ext_vector_type(8)));

__device__ __forceinline__ void gload16(const __bf16* g, __bf16* l) {
    __builtin_amdgcn_global_load_lds(
        (__attribute__((address_space(1))) void*)(g),
        (__attribute__((address_space(3))) void*)(l), 16, 0, 0);
}

// A-side tiled layout (32-row blocks): elem (row, c) at
//   (rowblk32 * NKT*4 + octet)*256 + (row&31)*8 + (c&7),  octet = c>>3
// B-side tiled layout (64-col blocks): (colblk64 * NKT*4 + octet)*512 + (col&63)*8 + e.

// ---------------- top-10 tasks, wave per row ----------------
__global__ __launch_bounds__(256) void k_topk(const float* __restrict__ beta,
                                              float* __restrict__ total_beta,
                                              int* __restrict__ tasks) {
    int wid = threadIdx.x >> 6, lane = threadIdx.x & 63;
    int row = blockIdx.x * 4 + wid;
    const float* bp = beta + (size_t)row * MTASK * LDIM;
    float v1, v2 = -INFINITY;
    {
        const float* p = bp + lane * LDIM;
        v1 = p[0] + p[1] + p[2] + p[3] + p[4];
        total_beta[(size_t)row * MTASK + lane] = v1;
    }
    if (lane + 64 < MTASK) {
        const float* p = bp + (lane + 64) * LDIM;
        v2 = p[0] + p[1] + p[2] + p[3] + p[4];
        total_beta[(size_t)row * MTASK + lane + 64] = v2;
    }
    for (int k = 0; k < MTOP; ++k) {
        float v; int idx;
        if (v1 >= v2) { v = v1; idx = lane; } else { v = v2; idx = lane + 64; }
        #pragma unroll
        for (int m = 1; m < 64; m <<= 1) {
            float vo = __shfl_xor(v, m, 64);
            int io = __shfl_xor(idx, m, 64);
            if (vo > v || (vo == v && io < idx)) { v = vo; idx = io; }
        }
        if (lane == 0) tasks[row * MTOP + k] = idx;
        if (idx == lane) v1 = -INFINITY;
        else if (idx == lane + 64) v2 = -INFINITY;
    }
}

// ---------------- neighbors, wave per row ----------------
__global__ __launch_bounds__(256) void k_nbrs(const float* __restrict__ total_beta,
                                              const int* __restrict__ tasks,
                                              int* __restrict__ neighbors) {
    int wid = threadIdx.x >> 6, lane = threadIdx.x & 63;
    int row = blockIdx.x * 4 + wid;
    int bt = row / NAG, i = row - bt * NAG;
    int tk[MTOP];
    #pragma unroll
    for (int k = 0; k < MTOP; ++k) tk[k] = tasks[row * MTOP + k];
    float v1 = -INFINITY;
    if (lane < NAG) {
        const float* tba = total_beta + ((size_t)bt * NAG + lane) * MTASK;
        float mx = -INFINITY;
        #pragma unroll
        for (int k = 0; k < MTOP; ++k) mx = fmaxf(mx, tba[tk[k]]);
        v1 = (lane == i) ? -INFINITY : mx;
    }
    for (int k = 0; k < NNB; ++k) {
        float v = v1; int idx = lane;
        #pragma unroll
        for (int m = 1; m < 64; m <<= 1) {
            float vo = __shfl_xor(v, m, 64);
            int io = __shfl_xor(idx, m, 64);
            if (vo > v || (vo == v && io < idx)) { v = vo; idx = io; }
        }
        if (lane == 0) neighbors[row * NNB + k] = idx;
        if (idx == lane) v1 = -INFINITY;
    }
}

// ---------------- build inputs: LDS-staged gather, 8 rows/block, 32-row-block tiled out ----
__global__ __launch_bounds__(256) void k_build_inputs(
    const float* __restrict__ beta, const float* __restrict__ actions,
    const float* __restrict__ power, const int* __restrict__ prev,
    const int* __restrict__ tasks, const int* __restrict__ neighbors,
    __bf16* __restrict__ Ah, __bf16* __restrict__ Al) {
    int b = blockIdx.x;                 // rows [b*8, b*8+8)
    int t = threadIdx.x;
    __shared__ int tkv[8][MTOP], nbv[8][NNB], pav[8][NNB];
    __shared__ float pwv[8][NNB];
    __shared__ float fbuf[8][500];
    __shared__ float abuf[8][1004];
    if (t < 80) {
        int lr = t / 10, j = t - lr * 10;
        int row = b * 8 + lr;
        int bt = row / NAG;
        int nbj = neighbors[row * NNB + j];
        nbv[lr][j] = nbj;
        pav[lr][j] = prev[bt * NAG + nbj];
        pwv[lr][j] = power[bt * NAG + nbj];
        tkv[lr][j] = tasks[row * MTOP + j];
    }
    __syncthreads();
    int row0 = b * 8;
    #pragma unroll
    for (int it = 0; it < 4; ++it) {
        int idx = t + it * 256;
        if (idx < 800) {
            int l = idx / 100, p = idx - l * 100;
            int k = p / 10, j = p - k * 10;
            int row = row0 + l;
            int bt = row / NAG;
            const float* src = beta + ((size_t)(bt * NAG + nbv[l][j]) * MTASK
                                       + tkv[l][k]) * LDIM;
            int c0 = k * 50 + j * 5;
            #pragma unroll
            for (int i = 0; i < 5; ++i) fbuf[l][c0 + i] = src[i];
        }
    }
    #pragma unroll
    for (int it = 0; it < 8; ++it) {
        int idx = t + it * 256;
        if (idx < 2000) {
            int l = idx / 250, v = idx - l * 250;
            int j = v / 25, q = v - j * 25;
            int row = row0 + l;
            int bt = row / NAG;
            f32x4 a = *(const f32x4*)&actions[(size_t)(bt * NAG + nbv[l][j]) * MTASK + q * 4];
            *(f32x4*)&abuf[l][j * 100 + q * 4] = a;
        }
    }
    __syncthreads();
    int l = t & 7, og = t >> 3;
    int row = row0 + l;
    int rb = row >> 5, rlo = row & 31;
    #pragma unroll
    for (int s = 0; s < 7; ++s) {
        int o = og + 32 * s;
        if (o < 208) {                  // NKT1*4
            __bf16 h8[8], l8[8];
            #pragma unroll
            for (int e = 0; e < 8; ++e) {
                int c = o * 8 + e;
                float f;
                if (c < 500) {
                    f = fbuf[l][c];
                } else if (c < 1500) {
                    f = abuf[l][c - 500];
                } else if (c < 1510) {
                    f = pwv[l][c - 1500];
                } else if (c < 1610) {
                    int r2 = c - 1510, k = r2 / NNB, j = r2 - k * NNB;
                    f = (tkv[l][k] == pav[l][j]) ? 1.f : 0.f;
                } else {
                    f = 0.f;
                }
                __bf16 h = (__bf16)f;
                h8[e] = h;
                l8[e] = (__bf16)(f - (float)h);
            }
            size_t off = ((size_t)rb * 208 + o) * 256 + rlo * 8;
            *(bf16x8*)&Ah[off] = *(bf16x8*)h8;
            *(bf16x8*)&Al[off] = *(bf16x8*)l8;
        }
    }
}

// ---------------- merged weight prep: W1 and W2 -> tiled hi-only (64-col blocks) ----
__global__ __launch_bounds__(256) void k_prep_wt(const float* __restrict__ W1,
                                                 const float* __restrict__ W2,
                                                 __bf16* __restrict__ T1,
                                                 __bf16* __restrict__ T2) {
    int bx = blockIdx.x, n0 = blockIdx.y * 64;
    const float* W; __bf16* T; int K, NKT, kp0;
    if (bx < KP1 / 64) { W = W1; T = T1; K = INDIM; NKT = NKT1; kp0 = bx * 64; }
    else               { W = W2; T = T2; K = HDIM;  NKT = NKT2; kp0 = (bx - KP1 / 64) * 64; }
    __shared__ float lds[64][65];
    int t = threadIdx.x;
    int cc = t & 63, r0 = t >> 6;
    #pragma unroll
    for (int i = 0; i < 16; ++i) {
        int rr = r0 + i * 4;
        int kp = kp0 + rr;
        lds[rr][cc] = (kp < K) ? W[(size_t)kp * HDIM + n0 + cc] : 0.f;
    }
    __syncthreads();
    int nblk = n0 >> 6;
    #pragma unroll
    for (int s = 0; s < 2; ++s) {
        int o = t + s * 256;
        int rn = o & 63, ko = o >> 6;
        int kp = kp0 + ko * 8;
        int kt = kp >> 5, kc = (kp >> 3) & 3;
        __bf16 h8[8];
        #pragma unroll
        for (int e = 0; e < 8; ++e) h8[e] = (__bf16)lds[ko * 8 + e][rn];
        size_t off = ((size_t)(nblk * NKT + kt) * 4 + kc) * 512 + rn * 8;
        *(bf16x8*)&T[off] = *(bf16x8*)h8;
    }
}

// ---------------- zero out ----------------
__global__ void k_zero(float* __restrict__ p, int n) {
    int i = blockIdx.x * 256 + threadIdx.x;
    if (i < n) p[i] = 0.f;
}

// ---------------- 2-pass split-bf16 GEMM, 32x128 tile, BK=64 ----------------
// Grid 1600 = 400 mt x 4 nt, XCD-bijective swizzle. LDS {Ah,Bh} 40KB dbuf;
// Al via per-wave register loads (same (lane,e)->k map; k-perm cancels in MFMA).
// MODE 0: epilogue = +bias, relu, hi/lo split, tiled write (feeds GEMM2).
// MODE 1: epilogue = +bias, relu, partial @W3 -> atomicAdd into out (b3 from nt==0).
template<int NKT, int MODE>
__global__ __launch_bounds__(256, 2) void k_gemm(
    const __bf16* __restrict__ Ahp, const __bf16* __restrict__ Alp,
    const __bf16* __restrict__ Bhp, const float* __restrict__ bias,
    __bf16* __restrict__ Ch, __bf16* __restrict__ Cl,
    const float* __restrict__ W3, const float* __restrict__ b3,
    float* __restrict__ outp) {
    constexpr int NST = NKT / 2;            // BK=64 steps
    __shared__ __align__(16) char smem[40960];
    __bf16* sAh = (__bf16*)smem;            // 2 bufs x 2048 bf16 (8 KB)
    __bf16* sB  = (__bf16*)(smem + 8192);   // 2 bufs x 8192 bf16 (32 KB)
    int tid = threadIdx.x, wid = tid >> 6, lane = tid & 63;
    int id = blockIdx.x;
    int swz = (id & 7) * 200 + (id >> 3);   // bijective: 1600 % 8 == 0
    int nt = swz & 3, mt = swz >> 2;        // mt in [0,400)

    auto stage = [&](int st, int buf) {
        int oct0 = st * 8;                  // 8 octets per step
        #pragma unroll
        for (int j = 0; j < 5; ++j) {
            int seg = wid + 4 * j;          // 0..19
            if (seg < 4) {
                gload16(Ahp + ((size_t)mt * NKT * 4 + oct0 + seg * 2) * 256 + lane * 8,
                        sAh + buf * 2048 + seg * 512);
            } else {
                int s = seg - 4, q = s >> 3, oo = s & 7;
                gload16(Bhp + ((size_t)(2 * nt + q) * NKT * 4 + oct0 + oo) * 512 + lane * 8,
                        sB + buf * 8192 + (oo >> 2) * 4096 + ((oo & 3) * 128 + q * 64) * 8);
            }
        }
    };

    int wr = wid >> 1, wc = wid & 1;        // wave-tile 16 rows x 64 cols
    int lrow = lane & 15, lk = lane >> 4;
    f32x4 acc[4] = {};

    stage(0, 0);
    for (int st = 0; st < NST; ++st) {
        int buf = st & 1;
        __syncthreads();
        // A-lo register loads first (oldest vmcnt entries)
        size_t ab = ((size_t)(mt * NKT + st * 2) * 4 + lk) * 256 + (wr * 16 + lrow) * 8;
        bf16x8 al0 = *(const bf16x8*)(Alp + ab);
        bf16x8 al1 = *(const bf16x8*)(Alp + ab + 1024);
        if (st + 1 < NST) stage(st + 1, buf ^ 1);
        int arow = (lk * 32 + wr * 16 + lrow) * 8;
        bf16x8 ah0 = *(const bf16x8*)(sAh + buf * 2048 + arow);
        bf16x8 ah1 = *(const bf16x8*)(sAh + buf * 2048 + 1024 + arow);
        int bcol = (lk * 128 + wc * 64 + lrow) * 8;
        bf16x8 b0[4], b1[4];
        #pragma unroll
        for (int j = 0; j < 4; ++j) {
            b0[j] = *(const bf16x8*)(sB + buf * 8192 + bcol + j * 128);
            b1[j] = *(const bf16x8*)(sB + buf * 8192 + 4096 + bcol + j * 128);
        }
        #pragma unroll
        for (int j = 0; j < 4; ++j) {
            acc[j] = __builtin_amdgcn_mfma_f32_16x16x32_bf16(ah0, b0[j], acc[j], 0, 0, 0);
            acc[j] = __builtin_amdgcn_mfma_f32_16x16x32_bf16(al0, b0[j], acc[j], 0, 0, 0);
            acc[j] = __builtin_amdgcn_mfma_f32_16x16x32_bf16(ah1, b1[j], acc[j], 0, 0, 0);
            acc[j] = __builtin_amdgcn_mfma_f32_16x16x32_bf16(al1, b1[j], acc[j], 0, 0, 0);
        }
    }

    // common: transpose acc into sE[32][132]
    __syncthreads();
    float* sE = (float*)smem;               // 32 x 132 fp32 = 16.9 KB
    #pragma unroll
    for (int j = 0; j < 4; ++j)
        #pragma unroll
        for (int r = 0; r < 4; ++r)
            sE[(wr * 16 + lk * 4 + r) * 132 + wc * 64 + j * 16 + lrow] = acc[j][r];
    __syncthreads();

    if constexpr (MODE == 0) {
        int l2 = tid & 31, og2 = tid >> 5;
        #pragma unroll
        for (int s2 = 0; s2 < 2; ++s2) {
            int o = og2 + 8 * s2;           // 0..15 local octet
            int n0 = nt * 128 + o * 8;
            f32x4 v0 = *(f32x4*)&sE[l2 * 132 + o * 8];
            f32x4 v1 = *(f32x4*)&sE[l2 * 132 + o * 8 + 4];
            f32x4 bb0 = *(const f32x4*)&bias[n0];
            f32x4 bb1 = *(const f32x4*)&bias[n0 + 4];
            __bf16 h8[8], l8[8];
            #pragma unroll
            for (int i = 0; i < 4; ++i) {
                float c = fmaxf(v0[i] + bb0[i], 0.f);
                __bf16 h = (__bf16)c;
                h8[i] = h; l8[i] = (__bf16)(c - (float)h);
                c = fmaxf(v1[i] + bb1[i], 0.f);
                h = (__bf16)c;
                h8[4 + i] = h; l8[4 + i] = (__bf16)(c - (float)h);
            }
            size_t off = ((size_t)mt * 64 + nt * 16 + o) * 256 + l2 * 8;
            *(bf16x8*)&Ch[off] = *(bf16x8*)h8;
            *(bf16x8*)&Cl[off] = *(bf16x8*)l8;
        }
    } else {
        // partial W3-dot: 8 threads per row, 16 cols each
        int row = tid >> 3, seg = tid & 7;
        float a11[NOUT];
        #pragma unroll
        for (int n = 0; n < NOUT; ++n) a11[n] = 0.f;
        #pragma unroll
        for (int c = 0; c < 16; ++c) {
            int col = seg * 16 + c;
            float h = fmaxf(sE[row * 132 + col] + bias[nt * 128 + col], 0.f);
            const float* w = W3 + (size_t)(nt * 128 + col) * NOUT;
            #pragma unroll
            for (int n = 0; n < NOUT; ++n) a11[n] += h * w[n];
        }
        #pragma unroll
        for (int d = 4; d >= 1; d >>= 1)
            #pragma unroll
            for (int n = 0; n < NOUT; ++n) a11[n] += __shfl_down(a11[n], d, 64);
        if (seg == 0) {
            int grow = mt * 32 + row;
            #pragma unroll
            for (int n = 0; n < NOUT; ++n) {
                float v = a11[n] + ((nt == 0) ? b3[n] : 0.f);
                atomicAdd(&outp[(size_t)grow * NOUT + n], v);
            }
        }
    }
}

extern "C" void kernel_launch(void* const* d_in, const int* in_sizes, int n_in,
                              void* d_out, int out_size, void* d_ws, size_t ws_size,
                              hipStream_t stream) {
    const float* beta    = (const float*)d_in[0];
    const float* actions = (const float*)d_in[1];
    const float* power   = (const float*)d_in[2];
    const int*   prev    = (const int*)d_in[3];
    const float* W1      = (const float*)d_in[4];
    const float* b1      = (const float*)d_in[5];
    const float* W2      = (const float*)d_in[6];
    const float* b2      = (const float*)d_in[7];
    const float* W3      = (const float*)d_in[8];
    const float* b3      = (const float*)d_in[9];
    float* out = (float*)d_out;

    char* ws = (char*)d_ws;
    size_t off = 0;
    auto alloc = [&](size_t bytes) { void* p = ws + off; off += (bytes + 255) & ~(size_t)255; return p; };
    float*  total_beta = (float*) alloc((size_t)NROWS * MTASK * 4);
    int*    tasks      = (int*)   alloc((size_t)NROWS * MTOP * 4);
    int*    neighbors  = (int*)   alloc((size_t)NROWS * NNB * 4);
    __bf16* Ah   = (__bf16*)alloc((size_t)NROWS * KP1 * 2);
    __bf16* Al   = (__bf16*)alloc((size_t)NROWS * KP1 * 2);
    __bf16* W1th = (__bf16*)alloc((size_t)HDIM * KP1 * 2);
    __bf16* W2th = (__bf16*)alloc((size_t)HDIM * HDIM * 2);
    __bf16* h1h  = (__bf16*)alloc((size_t)NROWS * HDIM * 2);
    __bf16* h1l  = (__bf16*)alloc((size_t)NROWS * HDIM * 2);

    k_zero<<<(NROWS * NOUT + 255) / 256, 256, 0, stream>>>(out, NROWS * NOUT);
    k_topk<<<NROWS / 4, 256, 0, stream>>>(beta, total_beta, tasks);
    k_nbrs<<<NROWS / 4, 256, 0, stream>>>(total_beta, tasks, neighbors);
    k_build_inputs<<<NROWS / 8, 256, 0, stream>>>(beta, actions, power, prev, tasks,
                                                  neighbors, Ah, Al);
    {
        dim3 gp(KP1 / 64 + HDIM / 64, HDIM / 64);
        k_prep_wt<<<gp, 256, 0, stream>>>(W1, W2, W1th, W2th);
    }
    // GEMM1: fused b1+relu+split epilogue -> h1h/h1l (tiled)
    k_gemm<NKT1, 0><<<1600, 256, 0, stream>>>(Ah, Al, W1th, b1, h1h, h1l,
                                              nullptr, nullptr, nullptr);
    // GEMM2: fused b2+relu+@W3+b3 -> atomic out
    k_gemm<NKT2, 1><<<1600, 256, 0, stream>>>(h1h, h1l, W2th, b2, nullptr, nullptr,
                                              W3, b3, out);
}

// Round 13
// 205.671 us; speedup vs baseline: 1.0150x; 1.0150x over previous
//
#include <hip/hip_runtime.h>
#include <math.h>

#define NB 8
#define NT 32
#define NAG 50
#define MTASK 100
#define MTOP 10
#define NNB 10
#define LDIM 5
#define HDIM 512
#define INDIM 1610
#define KP1 1664            // INDIM padded to multiple of 64
#define NKT1 (KP1/32)       // 52 k-chunks
#define NKT2 (HDIM/32)      // 16
#define NROWS (NB*NT*NAG)   // 12800
#define NOUT (MTOP+1)       // 11

typedef float f32x4 __attribute__((ext_vector_type(4)));
typedef __bf16 bf16x8 __attribute__((ext_vector_type(8)));

__device__ __forceinline__ void gload16(const __bf16* g, __bf16* l) {
    __builtin_amdgcn_global_load_lds(
        (__attribute__((address_space(1))) void*)(g),
        (__attribute__((address_space(3))) void*)(l), 16, 0, 0);
}

// A-side tiled layout (32-row blocks): elem (row, c) at
//   (rowblk32 * NKT*4 + octet)*256 + (row&31)*8 + (c&7),  octet = c>>3
// B-side tiled layout (64-col blocks): (colblk64 * NKT*4 + octet)*512 + (col&63)*8 + e.

// ---------------- top-10 tasks, wave per row ----------------
__global__ __launch_bounds__(256) void k_topk(const float* __restrict__ beta,
                                              float* __restrict__ total_beta,
                                              int* __restrict__ tasks) {
    int wid = threadIdx.x >> 6, lane = threadIdx.x & 63;
    int row = blockIdx.x * 4 + wid;
    const float* bp = beta + (size_t)row * MTASK * LDIM;
    float v1, v2 = -INFINITY;
    {
        const float* p = bp + lane * LDIM;
        v1 = p[0] + p[1] + p[2] + p[3] + p[4];
        total_beta[(size_t)row * MTASK + lane] = v1;
    }
    if (lane + 64 < MTASK) {
        const float* p = bp + (lane + 64) * LDIM;
        v2 = p[0] + p[1] + p[2] + p[3] + p[4];
        total_beta[(size_t)row * MTASK + lane + 64] = v2;
    }
    for (int k = 0; k < MTOP; ++k) {
        float v; int idx;
        if (v1 >= v2) { v = v1; idx = lane; } else { v = v2; idx = lane + 64; }
        #pragma unroll
        for (int m = 1; m < 64; m <<= 1) {
            float vo = __shfl_xor(v, m, 64);
            int io = __shfl_xor(idx, m, 64);
            if (vo > v || (vo == v && io < idx)) { v = vo; idx = io; }
        }
        if (lane == 0) tasks[row * MTOP + k] = idx;
        if (idx == lane) v1 = -INFINITY;
        else if (idx == lane + 64) v2 = -INFINITY;
    }
}

// ---------------- build inputs + fused neighbor selection, 8 rows/block ----------------
__global__ __launch_bounds__(256) void k_build_inputs(
    const float* __restrict__ beta, const float* __restrict__ actions,
    const float* __restrict__ power, const int* __restrict__ prev,
    const int* __restrict__ tasks, const float* __restrict__ total_beta,
    __bf16* __restrict__ Ah, __bf16* __restrict__ Al) {
    int b = blockIdx.x;                 // rows [b*8, b*8+8)
    int t = threadIdx.x;
    int wid = t >> 6, lane = t & 63;
    __shared__ int tkv[8][MTOP], nbv[8][NNB], pav[8][NNB];
    __shared__ float pwv[8][NNB];
    __shared__ float fbuf[8][500];
    __shared__ float abuf[8][1004];
    int row0 = b * 8;
    if (t < 80) {
        int lr = t / 10, j = t - lr * 10;
        tkv[lr][j] = tasks[(row0 + lr) * MTOP + j];
    }
    __syncthreads();
    // fused neighbors: wave w handles rows {2w, 2w+1}
    #pragma unroll
    for (int rr = 0; rr < 2; ++rr) {
        int lr = wid * 2 + rr;
        int row = row0 + lr;
        int bt = row / NAG, i = row - bt * NAG;
        float v1 = -INFINITY;
        if (lane < NAG) {
            const float* tba = total_beta + ((size_t)bt * NAG + lane) * MTASK;
            float mx = -INFINITY;
            #pragma unroll
            for (int k = 0; k < MTOP; ++k) mx = fmaxf(mx, tba[tkv[lr][k]]);
            v1 = (lane == i) ? -INFINITY : mx;
        }
        for (int k = 0; k < NNB; ++k) {
            float v = v1; int idx = lane;
            #pragma unroll
            for (int m = 1; m < 64; m <<= 1) {
                float vo = __shfl_xor(v, m, 64);
                int io = __shfl_xor(idx, m, 64);
                if (vo > v || (vo == v && io < idx)) { v = vo; idx = io; }
            }
            if (lane == 0) nbv[lr][k] = idx;
            if (idx == lane) v1 = -INFINITY;
        }
    }
    __syncthreads();
    if (t < 80) {
        int lr = t / 10, j = t - lr * 10;
        int row = row0 + lr;
        int bt = row / NAG;
        int nbj = nbv[lr][j];
        pav[lr][j] = prev[bt * NAG + nbj];
        pwv[lr][j] = power[bt * NAG + nbj];
    }
    __syncthreads();
    #pragma unroll
    for (int it = 0; it < 4; ++it) {
        int idx = t + it * 256;
        if (idx < 800) {
            int l = idx / 100, p = idx - l * 100;
            int k = p / 10, j = p - k * 10;
            int row = row0 + l;
            int bt = row / NAG;
            const float* src = beta + ((size_t)(bt * NAG + nbv[l][j]) * MTASK
                                       + tkv[l][k]) * LDIM;
            int c0 = k * 50 + j * 5;
            #pragma unroll
            for (int i = 0; i < 5; ++i) fbuf[l][c0 + i] = src[i];
        }
    }
    #pragma unroll
    for (int it = 0; it < 8; ++it) {
        int idx = t + it * 256;
        if (idx < 2000) {
            int l = idx / 250, v = idx - l * 250;
            int j = v / 25, q = v - j * 25;
            int row = row0 + l;
            int bt = row / NAG;
            f32x4 a = *(const f32x4*)&actions[(size_t)(bt * NAG + nbv[l][j]) * MTASK + q * 4];
            *(f32x4*)&abuf[l][j * 100 + q * 4] = a;
        }
    }
    __syncthreads();
    int l = t & 7, og = t >> 3;
    int row = row0 + l;
    int rb = row >> 5, rlo = row & 31;
    #pragma unroll
    for (int s = 0; s < 7; ++s) {
        int o = og + 32 * s;
        if (o < 208) {                  // NKT1*4
            __bf16 h8[8], l8[8];
            #pragma unroll
            for (int e = 0; e < 8; ++e) {
                int c = o * 8 + e;
                float f;
                if (c < 500) {
                    f = fbuf[l][c];
                } else if (c < 1500) {
                    f = abuf[l][c - 500];
                } else if (c < 1510) {
                    f = pwv[l][c - 1500];
                } else if (c < 1610) {
                    int r2 = c - 1510, k = r2 / NNB, j = r2 - k * NNB;
                    f = (tkv[l][k] == pav[l][j]) ? 1.f : 0.f;
                } else {
                    f = 0.f;
                }
                __bf16 h = (__bf16)f;
                h8[e] = h;
                l8[e] = (__bf16)(f - (float)h);
            }
            size_t off = ((size_t)rb * 208 + o) * 256 + rlo * 8;
            *(bf16x8*)&Ah[off] = *(bf16x8*)h8;
            *(bf16x8*)&Al[off] = *(bf16x8*)l8;
        }
    }
}

// ---------------- merged weight prep: W1 and W2 -> tiled hi-only (64-col blocks) ----
__global__ __launch_bounds__(256) void k_prep_wt(const float* __restrict__ W1,
                                                 const float* __restrict__ W2,
                                                 __bf16* __restrict__ T1,
                                                 __bf16* __restrict__ T2) {
    int bx = blockIdx.x, n0 = blockIdx.y * 64;
    const float* W; __bf16* T; int K, NKT, kp0;
    if (bx < KP1 / 64) { W = W1; T = T1; K = INDIM; NKT = NKT1; kp0 = bx * 64; }
    else               { W = W2; T = T2; K = HDIM;  NKT = NKT2; kp0 = (bx - KP1 / 64) * 64; }
    __shared__ float lds[64][65];
    int t = threadIdx.x;
    int cc = t & 63, r0 = t >> 6;
    #pragma unroll
    for (int i = 0; i < 16; ++i) {
        int rr = r0 + i * 4;
        int kp = kp0 + rr;
        lds[rr][cc] = (kp < K) ? W[(size_t)kp * HDIM + n0 + cc] : 0.f;
    }
    __syncthreads();
    int nblk = n0 >> 6;
    #pragma unroll
    for (int s = 0; s < 2; ++s) {
        int o = t + s * 256;
        int rn = o & 63, ko = o >> 6;
        int kp = kp0 + ko * 8;
        int kt = kp >> 5, kc = (kp >> 3) & 3;
        __bf16 h8[8];
        #pragma unroll
        for (int e = 0; e < 8; ++e) h8[e] = (__bf16)lds[ko * 8 + e][rn];
        size_t off = ((size_t)(nblk * NKT + kt) * 4 + kc) * 512 + rn * 8;
        *(bf16x8*)&T[off] = *(bf16x8*)h8;
    }
}

// ---------------- 2-pass split-bf16 GEMM, 32x128 tile, BK=32 ----------------
// Grid 1600 = 400 mt x 4 nt, XCD-bijective swizzle. LDS {Ah,Bh} 20KB dbuf;
// Al via per-wave register loads (same (lane,e)->k map; k-perm cancels in MFMA).
// MODE 0: epilogue = +bias, relu, hi/lo split, tiled write (feeds GEMM2).
// MODE 1: epilogue = +bias, relu, W3-slice dot (W3 in LDS) -> qpart[nt] (no atomics).
template<int NKT, int MODE>
__global__ __launch_bounds__(256, 4) void k_gemm(
    const __bf16* __restrict__ Ahp, const __bf16* __restrict__ Alp,
    const __bf16* __restrict__ Bhp, const float* __restrict__ bias,
    __bf16* __restrict__ Ch, __bf16* __restrict__ Cl,
    const float* __restrict__ W3, float* __restrict__ qpart) {
    __shared__ __align__(16) char smem[24064];
    __bf16* sAh = (__bf16*)smem;             // 2 bufs x 1024 bf16
    __bf16* sB  = (__bf16*)(smem + 4096);    // 2 bufs x 4096 bf16
    int tid = threadIdx.x, wid = tid >> 6, lane = tid & 63;
    int id = blockIdx.x;
    int swz = (id & 7) * 200 + (id >> 3);    // bijective: 1600 % 8 == 0
    int nt = swz & 3, mt = swz >> 2;         // mt in [0,400)

    auto stage = [&](int kk, int buf) {
        #pragma unroll
        for (int j = 0; j < 3; ++j) {
            int seg = wid + 4 * j;           // 0..11
            if (seg < 2) {
                gload16(Ahp + (size_t)(mt * NKT + kk) * 1024 + seg * 512 + lane * 8,
                        sAh + buf * 1024 + seg * 512);
            } else if (seg < 10) {
                int s = seg - 2, q = s >> 2, kc = s & 3;
                gload16(Bhp + ((size_t)((2 * nt + q) * NKT + kk) * 4 + kc) * 512 + lane * 8,
                        sB + buf * 4096 + (kc * 128 + q * 64) * 8);
            }
        }
    };

    int wr = wid >> 1, wc = wid & 1;         // wave-tile 16 rows x 64 cols
    int lrow = lane & 15, lk = lane >> 4;
    f32x4 acc[4] = {};

    stage(0, 0);
    for (int kk = 0; kk < NKT; ++kk) {
        int buf = kk & 1;
        __syncthreads();
        // A-lo register load first (oldest vmcnt entry -> counted wait, not drain)
        size_t abase = ((size_t)(mt * NKT + kk) * 4 + lk) * 256 + (wr * 16 + lrow) * 8;
        bf16x8 al = *(const bf16x8*)(Alp + abase);
        if (kk + 1 < NKT) stage(kk + 1, buf ^ 1);
        bf16x8 ah = *(const bf16x8*)(sAh + buf * 1024 + (lk * 32 + wr * 16 + lrow) * 8);
        bf16x8 bh[4];
        #pragma unroll
        for (int j = 0; j < 4; ++j)
            bh[j] = *(const bf16x8*)(sB + buf * 4096 + (lk * 128 + wc * 64 + j * 16 + lrow) * 8);
        #pragma unroll
        for (int j = 0; j < 4; ++j) {
            acc[j] = __builtin_amdgcn_mfma_f32_16x16x32_bf16(ah, bh[j], acc[j], 0, 0, 0);
            acc[j] = __builtin_amdgcn_mfma_f32_16x16x32_bf16(al, bh[j], acc[j], 0, 0, 0);
        }
    }

    // common: transpose acc into sE[32][132] (staging dead after this barrier)
    __syncthreads();
    float* sE = (float*)smem;                // 32 x 132 fp32 = 16.9 KB
    #pragma unroll
    for (int j = 0; j < 4; ++j)
        #pragma unroll
        for (int r = 0; r < 4; ++r)
            sE[(wr * 16 + lk * 4 + r) * 132 + wc * 64 + j * 16 + lrow] = acc[j][r];

    if constexpr (MODE == 0) {
        __syncthreads();
        int l2 = tid & 31, og2 = tid >> 5;
        #pragma unroll
        for (int s2 = 0; s2 < 2; ++s2) {
            int o = og2 + 8 * s2;            // 0..15 local octet
            int n0 = nt * 128 + o * 8;
            f32x4 v0 = *(f32x4*)&sE[l2 * 132 + o * 8];
            f32x4 v1 = *(f32x4*)&sE[l2 * 132 + o * 8 + 4];
            f32x4 bb0 = *(const f32x4*)&bias[n0];
            f32x4 bb1 = *(const f32x4*)&bias[n0 + 4];
            __bf16 h8[8], l8[8];
            #pragma unroll
            for (int i = 0; i < 4; ++i) {
                float c = fmaxf(v0[i] + bb0[i], 0.f);
                __bf16 h = (__bf16)c;
                h8[i] = h; l8[i] = (__bf16)(c - (float)h);
                c = fmaxf(v1[i] + bb1[i], 0.f);
                h = (__bf16)c;
                h8[4 + i] = h; l8[4 + i] = (__bf16)(c - (float)h);
            }
            size_t off = ((size_t)mt * 64 + nt * 16 + o) * 256 + l2 * 8;
            *(bf16x8*)&Ch[off] = *(bf16x8*)h8;
            *(bf16x8*)&Cl[off] = *(bf16x8*)l8;
        }
    } else {
        // stage W3 slice (128 x 11 = 5.6 KB) into LDS, coalesced
        float* W3s = (float*)(smem + 16896);
        for (int i = tid; i < 128 * NOUT; i += 256)
            W3s[i] = W3[nt * 128 * NOUT + i];
        __syncthreads();
        int row = tid >> 3, seg = tid & 7;   // 8 threads per row, 16 cols each
        float a11[NOUT];
        #pragma unroll
        for (int n = 0; n < NOUT; ++n) a11[n] = 0.f;
        #pragma unroll
        for (int c16 = 0; c16 < 16; ++c16) {
            int col = seg * 16 + c16;
            float h = fmaxf(sE[row * 132 + col] + bias[nt * 128 + col], 0.f);
            const float* w = W3s + col * NOUT;
            #pragma unroll
            for (int n = 0; n < NOUT; ++n) a11[n] += h * w[n];
        }
        #pragma unroll
        for (int d = 4; d >= 1; d >>= 1)
            #pragma unroll
            for (int n = 0; n < NOUT; ++n) a11[n] += __shfl_down(a11[n], d, 64);
        if (seg == 0) {
            int grow = mt * 32 + row;
            #pragma unroll
            for (int n = 0; n < NOUT; ++n)
                qpart[(size_t)nt * NROWS * NOUT + (size_t)grow * NOUT + n] = a11[n];
        }
    }
}

// ---------------- reduce 4 q-partials + b3 ----------------
__global__ __launch_bounds__(256) void k_qreduce(const float* __restrict__ qp,
                                                 const float* __restrict__ b3,
                                                 float* __restrict__ out) {
    int i = blockIdx.x * 256 + threadIdx.x;
    if (i < NROWS * NOUT) {
        int n = i % NOUT;
        const size_t P = (size_t)NROWS * NOUT;
        out[i] = b3[n] + qp[i] + qp[i + P] + qp[i + 2 * P] + qp[i + 3 * P];
    }
}

extern "C" void kernel_launch(void* const* d_in, const int* in_sizes, int n_in,
                              void* d_out, int out_size, void* d_ws, size_t ws_size,
                              hipStream_t stream) {
    const float* beta    = (const float*)d_in[0];
    const float* actions = (const float*)d_in[1];
    const float* power   = (const float*)d_in[2];
    const int*   prev    = (const int*)d_in[3];
    const float* W1      = (const float*)d_in[4];
    const float* b1      = (const float*)d_in[5];
    const float* W2      = (const float*)d_in[6];
    const float* b2      = (const float*)d_in[7];
    const float* W3      = (const float*)d_in[8];
    const float* b3      = (const float*)d_in[9];
    float* out = (float*)d_out;

    char* ws = (char*)d_ws;
    size_t off = 0;
    auto alloc = [&](size_t bytes) { void* p = ws + off; off += (bytes + 255) & ~(size_t)255; return p; };
    float*  total_beta = (float*) alloc((size_t)NROWS * MTASK * 4);
    int*    tasks      = (int*)   alloc((size_t)NROWS * MTOP * 4);
    __bf16* Ah   = (__bf16*)alloc((size_t)NROWS * KP1 * 2);
    __bf16* Al   = (__bf16*)alloc((size_t)NROWS * KP1 * 2);
    __bf16* W1th = (__bf16*)alloc((size_t)HDIM * KP1 * 2);
    __bf16* W2th = (__bf16*)alloc((size_t)HDIM * HDIM * 2);
    __bf16* h1h  = (__bf16*)alloc((size_t)NROWS * HDIM * 2);
    __bf16* h1l  = (__bf16*)alloc((size_t)NROWS * HDIM * 2);
    float*  qpart = (float*)alloc((size_t)4 * NROWS * NOUT * 4);

    k_topk<<<NROWS / 4, 256, 0, stream>>>(beta, total_beta, tasks);
    k_build_inputs<<<NROWS / 8, 256, 0, stream>>>(beta, actions, power, prev, tasks,
                                                  total_beta, Ah, Al);
    {
        dim3 gp(KP1 / 64 + HDIM / 64, HDIM / 64);
        k_prep_wt<<<gp, 256, 0, stream>>>(W1, W2, W1th, W2th);
    }
    // GEMM1: fused b1+relu+split epilogue -> h1h/h1l (tiled)
    k_gemm<NKT1, 0><<<1600, 256, 0, stream>>>(Ah, Al, W1th, b1, h1h, h1l,
                                              nullptr, nullptr);
    // GEMM2: fused b2+relu+W3-slice dot -> qpart (no atomics)
    k_gemm<NKT2, 1><<<1600, 256, 0, stream>>>(h1h, h1l, W2th, b2, nullptr, nullptr,
                                              W3, qpart);
    k_qreduce<<<(NROWS * NOUT + 255) / 256, 256, 0, stream>>>(qpart, b3, out);
}

// Round 14
// 197.178 us; speedup vs baseline: 1.0588x; 1.0431x over previous
//
#include <hip/hip_runtime.h>
#include <math.h>

#define NB 8
#define NT 32
#define NAG 50
#define MTASK 100
#define MTOP 10
#define NNB 10
#define LDIM 5
#define HDIM 512
#define INDIM 1610
#define KP1 1664            // INDIM padded to multiple of 64
#define NKT1 (KP1/32)       // 52 k-chunks
#define NKT2 (HDIM/32)      // 16
#define NROWS (NB*NT*NAG)   // 12800
#define NOUT (MTOP+1)       // 11

typedef float f32x4 __attribute__((ext_vector_type(4)));
typedef __bf16 bf16x8 __attribute__((ext_vector_type(8)));

__device__ __forceinline__ void gload16(const __bf16* g, __bf16* l) {
    __builtin_amdgcn_global_load_lds(
        (__attribute__((address_space(1))) void*)(g),
        (__attribute__((address_space(3))) void*)(l), 16, 0, 0);
}

// A-side tiled layout (32-row blocks): elem (row, c) at
//   (rowblk32 * NKT*4 + octet)*256 + (row&31)*8 + (c&7),  octet = c>>3
// B-side tiled layout (64-col blocks): (colblk64 * NKT*4 + octet)*512 + (col&63)*8 + e.

// ---------------- top-10 tasks, wave per row ----------------
__global__ __launch_bounds__(256) void k_topk(const float* __restrict__ beta,
                                              float* __restrict__ total_beta,
                                              int* __restrict__ tasks) {
    int wid = threadIdx.x >> 6, lane = threadIdx.x & 63;
    int row = blockIdx.x * 4 + wid;
    const float* bp = beta + (size_t)row * MTASK * LDIM;
    float v1, v2 = -INFINITY;
    {
        const float* p = bp + lane * LDIM;
        v1 = p[0] + p[1] + p[2] + p[3] + p[4];
        total_beta[(size_t)row * MTASK + lane] = v1;
    }
    if (lane + 64 < MTASK) {
        const float* p = bp + (lane + 64) * LDIM;
        v2 = p[0] + p[1] + p[2] + p[3] + p[4];
        total_beta[(size_t)row * MTASK + lane + 64] = v2;
    }
    for (int k = 0; k < MTOP; ++k) {
        float v; int idx;
        if (v1 >= v2) { v = v1; idx = lane; } else { v = v2; idx = lane + 64; }
        #pragma unroll
        for (int m = 1; m < 64; m <<= 1) {
            float vo = __shfl_xor(v, m, 64);
            int io = __shfl_xor(idx, m, 64);
            if (vo > v || (vo == v && io < idx)) { v = vo; idx = io; }
        }
        if (lane == 0) tasks[row * MTOP + k] = idx;
        if (idx == lane) v1 = -INFINITY;
        else if (idx == lane + 64) v2 = -INFINITY;
    }
}

// ---------------- neighbors, wave per row ----------------
__global__ __launch_bounds__(256) void k_nbrs(const float* __restrict__ total_beta,
                                              const int* __restrict__ tasks,
                                              int* __restrict__ neighbors) {
    int wid = threadIdx.x >> 6, lane = threadIdx.x & 63;
    int row = blockIdx.x * 4 + wid;
    int bt = row / NAG, i = row - bt * NAG;
    int tk[MTOP];
    #pragma unroll
    for (int k = 0; k < MTOP; ++k) tk[k] = tasks[row * MTOP + k];
    float v1 = -INFINITY;
    if (lane < NAG) {
        const float* tba = total_beta + ((size_t)bt * NAG + lane) * MTASK;
        float mx = -INFINITY;
        #pragma unroll
        for (int k = 0; k < MTOP; ++k) mx = fmaxf(mx, tba[tk[k]]);
        v1 = (lane == i) ? -INFINITY : mx;
    }
    for (int k = 0; k < NNB; ++k) {
        float v = v1; int idx = lane;
        #pragma unroll
        for (int m = 1; m < 64; m <<= 1) {
            float vo = __shfl_xor(v, m, 64);
            int io = __shfl_xor(idx, m, 64);
            if (vo > v || (vo == v && io < idx)) { v = vo; idx = io; }
        }
        if (lane == 0) neighbors[row * NNB + k] = idx;
        if (idx == lane) v1 = -INFINITY;
    }
}

// ---------------- build inputs: LDS-staged gather, 8 rows/block, 32-row-block tiled out ----
__global__ __launch_bounds__(256) void k_build_inputs(
    const float* __restrict__ beta, const float* __restrict__ actions,
    const float* __restrict__ power, const int* __restrict__ prev,
    const int* __restrict__ tasks, const int* __restrict__ neighbors,
    __bf16* __restrict__ Ah, __bf16* __restrict__ Al) {
    int b = blockIdx.x;                 // rows [b*8, b*8+8)
    int t = threadIdx.x;
    __shared__ int tkv[8][MTOP], nbv[8][NNB], pav[8][NNB];
    __shared__ float pwv[8][NNB];
    __shared__ float fbuf[8][500];
    __shared__ float abuf[8][1004];
    if (t < 80) {
        int lr = t / 10, j = t - lr * 10;
        int row = b * 8 + lr;
        int bt = row / NAG;
        int nbj = neighbors[row * NNB + j];
        nbv[lr][j] = nbj;
        pav[lr][j] = prev[bt * NAG + nbj];
        pwv[lr][j] = power[bt * NAG + nbj];
        tkv[lr][j] = tasks[row * MTOP + j];
    }
    __syncthreads();
    int row0 = b * 8;
    #pragma unroll
    for (int it = 0; it < 4; ++it) {
        int idx = t + it * 256;
        if (idx < 800) {
            int l = idx / 100, p = idx - l * 100;
            int k = p / 10, j = p - k * 10;
            int row = row0 + l;
            int bt = row / NAG;
            const float* src = beta + ((size_t)(bt * NAG + nbv[l][j]) * MTASK
                                       + tkv[l][k]) * LDIM;
            int c0 = k * 50 + j * 5;
            #pragma unroll
            for (int i = 0; i < 5; ++i) fbuf[l][c0 + i] = src[i];
        }
    }
    #pragma unroll
    for (int it = 0; it < 8; ++it) {
        int idx = t + it * 256;
        if (idx < 2000) {
            int l = idx / 250, v = idx - l * 250;
            int j = v / 25, q = v - j * 25;
            int row = row0 + l;
            int bt = row / NAG;
            f32x4 a = *(const f32x4*)&actions[(size_t)(bt * NAG + nbv[l][j]) * MTASK + q * 4];
            *(f32x4*)&abuf[l][j * 100 + q * 4] = a;
        }
    }
    __syncthreads();
    int l = t & 7, og = t >> 3;
    int row = row0 + l;
    int rb = row >> 5, rlo = row & 31;
    #pragma unroll
    for (int s = 0; s < 7; ++s) {
        int o = og + 32 * s;
        if (o < 208) {                  // NKT1*4
            __bf16 h8[8], l8[8];
            #pragma unroll
            for (int e = 0; e < 8; ++e) {
                int c = o * 8 + e;
                float f;
                if (c < 500) {
                    f = fbuf[l][c];
                } else if (c < 1500) {
                    f = abuf[l][c - 500];
                } else if (c < 1510) {
                    f = pwv[l][c - 1500];
                } else if (c < 1610) {
                    int r2 = c - 1510, k = r2 / NNB, j = r2 - k * NNB;
                    f = (tkv[l][k] == pav[l][j]) ? 1.f : 0.f;
                } else {
                    f = 0.f;
                }
                __bf16 h = (__bf16)f;
                h8[e] = h;
                l8[e] = (__bf16)(f - (float)h);
            }
            size_t off = ((size_t)rb * 208 + o) * 256 + rlo * 8;
            *(bf16x8*)&Ah[off] = *(bf16x8*)h8;
            *(bf16x8*)&Al[off] = *(bf16x8*)l8;
        }
    }
}

// ---------------- merged weight prep: W1 and W2 -> tiled hi-only (64-col blocks) ----
__global__ __launch_bounds__(256) void k_prep_wt(const float* __restrict__ W1,
                                                 const float* __restrict__ W2,
                                                 __bf16* __restrict__ T1,
                                                 __bf16* __restrict__ T2) {
    int bx = blockIdx.x, n0 = blockIdx.y * 64;
    const float* W; __bf16* T; int K, NKT, kp0;
    if (bx < KP1 / 64) { W = W1; T = T1; K = INDIM; NKT = NKT1; kp0 = bx * 64; }
    else               { W = W2; T = T2; K = HDIM;  NKT = NKT2; kp0 = (bx - KP1 / 64) * 64; }
    __shared__ float lds[64][65];
    int t = threadIdx.x;
    int cc = t & 63, r0 = t >> 6;
    #pragma unroll
    for (int i = 0; i < 16; ++i) {
        int rr = r0 + i * 4;
        int kp = kp0 + rr;
        lds[rr][cc] = (kp < K) ? W[(size_t)kp * HDIM + n0 + cc] : 0.f;
    }
    __syncthreads();
    int nblk = n0 >> 6;
    #pragma unroll
    for (int s = 0; s < 2; ++s) {
        int o = t + s * 256;
        int rn = o & 63, ko = o >> 6;
        int kp = kp0 + ko * 8;
        int kt = kp >> 5, kc = (kp >> 3) & 3;
        __bf16 h8[8];
        #pragma unroll
        for (int e = 0; e < 8; ++e) h8[e] = (__bf16)lds[ko * 8 + e][rn];
        size_t off = ((size_t)(nblk * NKT + kt) * 4 + kc) * 512 + rn * 8;
        *(bf16x8*)&T[off] = *(bf16x8*)h8;
    }
}

// ---------------- 2-pass split-bf16 GEMM, 32x128 tile, BK=32 ----------------
// Grid 1600 = 400 mt x 4 nt, XCD-bijective swizzle. LDS {Ah,Bh} 20KB dbuf;
// Al via per-wave register loads (same (lane,e)->k map; k-perm cancels in MFMA).
// MODE 0: epilogue = +bias, relu, hi/lo split, tiled write (feeds GEMM2).
// MODE 1: epilogue = +bias, relu, W3-slice dot (W3 in LDS) -> qpart[nt] (no atomics).
template<int NKT, int MODE>
__global__ __launch_bounds__(256, 4) void k_gemm(
    const __bf16* __restrict__ Ahp, const __bf16* __restrict__ Alp,
    const __bf16* __restrict__ Bhp, const float* __restrict__ bias,
    __bf16* __restrict__ Ch, __bf16* __restrict__ Cl,
    const float* __restrict__ W3, float* __restrict__ qpart) {
    __shared__ __align__(16) char smem[24064];
    __bf16* sAh = (__bf16*)smem;             // 2 bufs x 1024 bf16
    __bf16* sB  = (__bf16*)(smem + 4096);    // 2 bufs x 4096 bf16
    int tid = threadIdx.x, wid = tid >> 6, lane = tid & 63;
    int id = blockIdx.x;
    int swz = (id & 7) * 200 + (id >> 3);    // bijective: 1600 % 8 == 0
    int nt = swz & 3, mt = swz >> 2;         // mt in [0,400)

    auto stage = [&](int kk, int buf) {
        #pragma unroll
        for (int j = 0; j < 3; ++j) {
            int seg = wid + 4 * j;           // 0..11
            if (seg < 2) {
                gload16(Ahp + (size_t)(mt * NKT + kk) * 1024 + seg * 512 + lane * 8,
                        sAh + buf * 1024 + seg * 512);
            } else if (seg < 10) {
                int s = seg - 2, q = s >> 2, kc = s & 3;
                gload16(Bhp + ((size_t)((2 * nt + q) * NKT + kk) * 4 + kc) * 512 + lane * 8,
                        sB + buf * 4096 + (kc * 128 + q * 64) * 8);
            }
        }
    };

    int wr = wid >> 1, wc = wid & 1;         // wave-tile 16 rows x 64 cols
    int lrow = lane & 15, lk = lane >> 4;
    f32x4 acc[4] = {};

    stage(0, 0);
    for (int kk = 0; kk < NKT; ++kk) {
        int buf = kk & 1;
        __syncthreads();
        // A-lo register load first (oldest vmcnt entry -> counted wait, not drain)
        size_t abase = ((size_t)(mt * NKT + kk) * 4 + lk) * 256 + (wr * 16 + lrow) * 8;
        bf16x8 al = *(const bf16x8*)(Alp + abase);
        if (kk + 1 < NKT) stage(kk + 1, buf ^ 1);
        bf16x8 ah = *(const bf16x8*)(sAh + buf * 1024 + (lk * 32 + wr * 16 + lrow) * 8);
        bf16x8 bh[4];
        #pragma unroll
        for (int j = 0; j < 4; ++j)
            bh[j] = *(const bf16x8*)(sB + buf * 4096 + (lk * 128 + wc * 64 + j * 16 + lrow) * 8);
        #pragma unroll
        for (int j = 0; j < 4; ++j) {
            acc[j] = __builtin_amdgcn_mfma_f32_16x16x32_bf16(ah, bh[j], acc[j], 0, 0, 0);
            acc[j] = __builtin_amdgcn_mfma_f32_16x16x32_bf16(al, bh[j], acc[j], 0, 0, 0);
        }
    }

    // common: transpose acc into sE[32][132] (staging dead after this barrier)
    __syncthreads();
    float* sE = (float*)smem;                // 32 x 132 fp32 = 16.9 KB
    #pragma unroll
    for (int j = 0; j < 4; ++j)
        #pragma unroll
        for (int r = 0; r < 4; ++r)
            sE[(wr * 16 + lk * 4 + r) * 132 + wc * 64 + j * 16 + lrow] = acc[j][r];

    if constexpr (MODE == 0) {
        __syncthreads();
        int l2 = tid & 31, og2 = tid >> 5;
        #pragma unroll
        for (int s2 = 0; s2 < 2; ++s2) {
            int o = og2 + 8 * s2;            // 0..15 local octet
            int n0 = nt * 128 + o * 8;
            f32x4 v0 = *(f32x4*)&sE[l2 * 132 + o * 8];
            f32x4 v1 = *(f32x4*)&sE[l2 * 132 + o * 8 + 4];
            f32x4 bb0 = *(const f32x4*)&bias[n0];
            f32x4 bb1 = *(const f32x4*)&bias[n0 + 4];
            __bf16 h8[8], l8[8];
            #pragma unroll
            for (int i = 0; i < 4; ++i) {
                float c = fmaxf(v0[i] + bb0[i], 0.f);
                __bf16 h = (__bf16)c;
                h8[i] = h; l8[i] = (__bf16)(c - (float)h);
                c = fmaxf(v1[i] + bb1[i], 0.f);
                h = (__bf16)c;
                h8[4 + i] = h; l8[4 + i] = (__bf16)(c - (float)h);
            }
            size_t off = ((size_t)mt * 64 + nt * 16 + o) * 256 + l2 * 8;
            *(bf16x8*)&Ch[off] = *(bf16x8*)h8;
            *(bf16x8*)&Cl[off] = *(bf16x8*)l8;
        }
    } else {
        // stage W3 slice (128 x 11 = 5.6 KB) into LDS, coalesced
        float* W3s = (float*)(smem + 16896);
        for (int i = tid; i < 128 * NOUT; i += 256)
            W3s[i] = W3[nt * 128 * NOUT + i];
        __syncthreads();
        int row = tid >> 3, seg = tid & 7;   // 8 threads per row, 16 cols each
        float a11[NOUT];
        #pragma unroll
        for (int n = 0; n < NOUT; ++n) a11[n] = 0.f;
        #pragma unroll
        for (int c16 = 0; c16 < 16; ++c16) {
            int col = seg * 16 + c16;
            float h = fmaxf(sE[row * 132 + col] + bias[nt * 128 + col], 0.f);
            const float* w = W3s + col * NOUT;
            #pragma unroll
            for (int n = 0; n < NOUT; ++n) a11[n] += h * w[n];
        }
        #pragma unroll
        for (int d = 4; d >= 1; d >>= 1)
            #pragma unroll
            for (int n = 0; n < NOUT; ++n) a11[n] += __shfl_down(a11[n], d, 64);
        if (seg == 0) {
            int grow = mt * 32 + row;
            #pragma unroll
            for (int n = 0; n < NOUT; ++n)
                qpart[(size_t)nt * NROWS * NOUT + (size_t)grow * NOUT + n] = a11[n];
        }
    }
}

// ---------------- reduce 4 q-partials + b3 ----------------
__global__ __launch_bounds__(256) void k_qreduce(const float* __restrict__ qp,
                                                 const float* __restrict__ b3,
                                                 float* __restrict__ out) {
    int i = blockIdx.x * 256 + threadIdx.x;
    if (i < NROWS * NOUT) {
        int n = i % NOUT;
        const size_t P = (size_t)NROWS * NOUT;
        out[i] = b3[n] + qp[i] + qp[i + P] + qp[i + 2 * P] + qp[i + 3 * P];
    }
}

extern "C" void kernel_launch(void* const* d_in, const int* in_sizes, int n_in,
                              void* d_out, int out_size, void* d_ws, size_t ws_size,
                              hipStream_t stream) {
    const float* beta    = (const float*)d_in[0];
    const float* actions = (const float*)d_in[1];
    const float* power   = (const float*)d_in[2];
    const int*   prev    = (const int*)d_in[3];
    const float* W1      = (const float*)d_in[4];
    const float* b1      = (const float*)d_in[5];
    const float* W2      = (const float*)d_in[6];
    const float* b2      = (const float*)d_in[7];
    const float* W3      = (const float*)d_in[8];
    const float* b3      = (const float*)d_in[9];
    float* out = (float*)d_out;

    char* ws = (char*)d_ws;
    size_t off = 0;
    auto alloc = [&](size_t bytes) { void* p = ws + off; off += (bytes + 255) & ~(size_t)255; return p; };
    float*  total_beta = (float*) alloc((size_t)NROWS * MTASK * 4);
    int*    tasks      = (int*)   alloc((size_t)NROWS * MTOP * 4);
    int*    neighbors  = (int*)   alloc((size_t)NROWS * NNB * 4);
    __bf16* Ah   = (__bf16*)alloc((size_t)NROWS * KP1 * 2);
    __bf16* Al   = (__bf16*)alloc((size_t)NROWS * KP1 * 2);
    __bf16* W1th = (__bf16*)alloc((size_t)HDIM * KP1 * 2);
    __bf16* W2th = (__bf16*)alloc((size_t)HDIM * HDIM * 2);
    __bf16* h1h  = (__bf16*)alloc((size_t)NROWS * HDIM * 2);
    __bf16* h1l  = (__bf16*)alloc((size_t)NROWS * HDIM * 2);
    float*  qpart = (float*)alloc((size_t)4 * NROWS * NOUT * 4);

    k_topk<<<NROWS / 4, 256, 0, stream>>>(beta, total_beta, tasks);
    k_nbrs<<<NROWS / 4, 256, 0, stream>>>(total_beta, tasks, neighbors);
    k_build_inputs<<<NROWS / 8, 256, 0, stream>>>(beta, actions, power, prev, tasks,
                                                  neighbors, Ah, Al);
    {
        dim3 gp(KP1 / 64 + HDIM / 64, HDIM / 64);
        k_prep_wt<<<gp, 256, 0, stream>>>(W1, W2, W1th, W2th);
    }
    // GEMM1: fused b1+relu+split epilogue -> h1h/h1l (tiled)
    k_gemm<NKT1, 0><<<1600, 256, 0, stream>>>(Ah, Al, W1th, b1, h1h, h1l,
                                              nullptr, nullptr);
    // GEMM2: fused b2+relu+W3-slice dot -> qpart (no atomics)
    k_gemm<NKT2, 1><<<1600, 256, 0, stream>>>(h1h, h1l, W2th, b2, nullptr, nullptr,
                                              W3, qpart);
    k_qreduce<<<(NROWS * NOUT + 255) / 256, 256, 0, stream>>>(qpart, b3, out);
}

// Round 15
// 150.148 us; speedup vs baseline: 1.3904x; 1.3132x over previous
//
#include <hip/hip_runtime.h>
#include <math.h>

#define NB 8
#define NT 32
#define NAG 50
#define MTASK 100
#define MTOP 10
#define NNB 10
#define LDIM 5
#define HDIM 512
#define INDIM 1610
#define KP1 1664            // INDIM padded to multiple of 64
#define NKT1 (KP1/32)       // 52 k-chunks
#define NKT2 (HDIM/32)      // 16
#define NROWS (NB*NT*NAG)   // 12800
#define NOUT (MTOP+1)       // 11

typedef float f32x4 __attribute__((ext_vector_type(4)));
typedef _Float16 f16;
typedef _Float16 f16x8 __attribute__((ext_vector_type(8)));

__device__ __forceinline__ void gload16(const void* g, void* l) {
    __builtin_amdgcn_global_load_lds(
        (__attribute__((address_space(1))) void*)(g),
        (__attribute__((address_space(3))) void*)(l), 16, 0, 0);
}

// A-side tiled layout (32-row blocks): elem (row, c) at
//   (rowblk32 * NKT*4 + octet)*256 + (row&31)*8 + (c&7),  octet = c>>3
// B-side tiled layout (64-col blocks): (colblk64 * NKT*4 + octet)*512 + (col&63)*8 + e.

// ---------------- top-10 tasks, wave per row ----------------
__global__ __launch_bounds__(256) void k_topk(const float* __restrict__ beta,
                                              float* __restrict__ total_beta,
                                              int* __restrict__ tasks) {
    int wid = threadIdx.x >> 6, lane = threadIdx.x & 63;
    int row = blockIdx.x * 4 + wid;
    const float* bp = beta + (size_t)row * MTASK * LDIM;
    float v1, v2 = -INFINITY;
    {
        const float* p = bp + lane * LDIM;
        v1 = p[0] + p[1] + p[2] + p[3] + p[4];
        total_beta[(size_t)row * MTASK + lane] = v1;
    }
    if (lane + 64 < MTASK) {
        const float* p = bp + (lane + 64) * LDIM;
        v2 = p[0] + p[1] + p[2] + p[3] + p[4];
        total_beta[(size_t)row * MTASK + lane + 64] = v2;
    }
    for (int k = 0; k < MTOP; ++k) {
        float v; int idx;
        if (v1 >= v2) { v = v1; idx = lane; } else { v = v2; idx = lane + 64; }
        #pragma unroll
        for (int m = 1; m < 64; m <<= 1) {
            float vo = __shfl_xor(v, m, 64);
            int io = __shfl_xor(idx, m, 64);
            if (vo > v || (vo == v && io < idx)) { v = vo; idx = io; }
        }
        if (lane == 0) tasks[row * MTOP + k] = idx;
        if (idx == lane) v1 = -INFINITY;
        else if (idx == lane + 64) v2 = -INFINITY;
    }
}

// ---------------- neighbors, wave per row ----------------
__global__ __launch_bounds__(256) void k_nbrs(const float* __restrict__ total_beta,
                                              const int* __restrict__ tasks,
                                              int* __restrict__ neighbors) {
    int wid = threadIdx.x >> 6, lane = threadIdx.x & 63;
    int row = blockIdx.x * 4 + wid;
    int bt = row / NAG, i = row - bt * NAG;
    int tk[MTOP];
    #pragma unroll
    for (int k = 0; k < MTOP; ++k) tk[k] = tasks[row * MTOP + k];
    float v1 = -INFINITY;
    if (lane < NAG) {
        const float* tba = total_beta + ((size_t)bt * NAG + lane) * MTASK;
        float mx = -INFINITY;
        #pragma unroll
        for (int k = 0; k < MTOP; ++k) mx = fmaxf(mx, tba[tk[k]]);
        v1 = (lane == i) ? -INFINITY : mx;
    }
    for (int k = 0; k < NNB; ++k) {
        float v = v1; int idx = lane;
        #pragma unroll
        for (int m = 1; m < 64; m <<= 1) {
            float vo = __shfl_xor(v, m, 64);
            int io = __shfl_xor(idx, m, 64);
            if (vo > v || (vo == v && io < idx)) { v = vo; idx = io; }
        }
        if (lane == 0) neighbors[row * NNB + k] = idx;
        if (idx == lane) v1 = -INFINITY;
    }
}

// ---------------- build inputs: LDS-staged gather, 8 rows/block, fp16 tiled out ----
__global__ __launch_bounds__(256) void k_build_inputs(
    const float* __restrict__ beta, const float* __restrict__ actions,
    const float* __restrict__ power, const int* __restrict__ prev,
    const int* __restrict__ tasks, const int* __restrict__ neighbors,
    f16* __restrict__ A) {
    int b = blockIdx.x;                 // rows [b*8, b*8+8)
    int t = threadIdx.x;
    __shared__ int tkv[8][MTOP], nbv[8][NNB], pav[8][NNB];
    __shared__ float pwv[8][NNB];
    __shared__ float fbuf[8][500];
    __shared__ float abuf[8][1004];
    if (t < 80) {
        int lr = t / 10, j = t - lr * 10;
        int row = b * 8 + lr;
        int bt = row / NAG;
        int nbj = neighbors[row * NNB + j];
        nbv[lr][j] = nbj;
        pav[lr][j] = prev[bt * NAG + nbj];
        pwv[lr][j] = power[bt * NAG + nbj];
        tkv[lr][j] = tasks[row * MTOP + j];
    }
    __syncthreads();
    int row0 = b * 8;
    #pragma unroll
    for (int it = 0; it < 4; ++it) {
        int idx = t + it * 256;
        if (idx < 800) {
            int l = idx / 100, p = idx - l * 100;
            int k = p / 10, j = p - k * 10;
            int row = row0 + l;
            int bt = row / NAG;
            const float* src = beta + ((size_t)(bt * NAG + nbv[l][j]) * MTASK
                                       + tkv[l][k]) * LDIM;
            int c0 = k * 50 + j * 5;
            #pragma unroll
            for (int i = 0; i < 5; ++i) fbuf[l][c0 + i] = src[i];
        }
    }
    #pragma unroll
    for (int it = 0; it < 8; ++it) {
        int idx = t + it * 256;
        if (idx < 2000) {
            int l = idx / 250, v = idx - l * 250;
            int j = v / 25, q = v - j * 25;
            int row = row0 + l;
            int bt = row / NAG;
            f32x4 a = *(const f32x4*)&actions[(size_t)(bt * NAG + nbv[l][j]) * MTASK + q * 4];
            *(f32x4*)&abuf[l][j * 100 + q * 4] = a;
        }
    }
    __syncthreads();
    int l = t & 7, og = t >> 3;
    int row = row0 + l;
    int rb = row >> 5, rlo = row & 31;
    #pragma unroll
    for (int s = 0; s < 7; ++s) {
        int o = og + 32 * s;
        if (o < 208) {                  // NKT1*4
            f16 h8[8];
            #pragma unroll
            for (int e = 0; e < 8; ++e) {
                int c = o * 8 + e;
                float f;
                if (c < 500) {
                    f = fbuf[l][c];
                } else if (c < 1500) {
                    f = abuf[l][c - 500];
                } else if (c < 1510) {
                    f = pwv[l][c - 1500];
                } else if (c < 1610) {
                    int r2 = c - 1510, k = r2 / NNB, j = r2 - k * NNB;
                    f = (tkv[l][k] == pav[l][j]) ? 1.f : 0.f;
                } else {
                    f = 0.f;
                }
                h8[e] = (f16)f;
            }
            size_t off = ((size_t)rb * 208 + o) * 256 + rlo * 8;
            *(f16x8*)&A[off] = *(f16x8*)h8;
        }
    }
}

// ---------------- merged weight prep: W1 and W2 -> tiled fp16 (64-col blocks) ----
__global__ __launch_bounds__(256) void k_prep_wt(const float* __restrict__ W1,
                                                 const float* __restrict__ W2,
                                                 f16* __restrict__ T1,
                                                 f16* __restrict__ T2) {
    int bx = blockIdx.x, n0 = blockIdx.y * 64;
    const float* W; f16* T; int K, NKT, kp0;
    if (bx < KP1 / 64) { W = W1; T = T1; K = INDIM; NKT = NKT1; kp0 = bx * 64; }
    else               { W = W2; T = T2; K = HDIM;  NKT = NKT2; kp0 = (bx - KP1 / 64) * 64; }
    __shared__ float lds[64][65];
    int t = threadIdx.x;
    int cc = t & 63, r0 = t >> 6;
    #pragma unroll
    for (int i = 0; i < 16; ++i) {
        int rr = r0 + i * 4;
        int kp = kp0 + rr;
        lds[rr][cc] = (kp < K) ? W[(size_t)kp * HDIM + n0 + cc] : 0.f;
    }
    __syncthreads();
    int nblk = n0 >> 6;
    #pragma unroll
    for (int s = 0; s < 2; ++s) {
        int o = t + s * 256;
        int rn = o & 63, ko = o >> 6;
        int kp = kp0 + ko * 8;
        int kt = kp >> 5, kc = (kp >> 3) & 3;
        f16 h8[8];
        #pragma unroll
        for (int e = 0; e < 8; ++e) h8[e] = (f16)lds[ko * 8 + e][rn];
        size_t off = ((size_t)(nblk * NKT + kt) * 4 + kc) * 512 + rn * 8;
        *(f16x8*)&T[off] = *(f16x8*)h8;
    }
}

// ---------------- single-pass fp16 MFMA GEMM, 32x128 tile, BK=32 ----------------
// Grid 1600 = 400 mt x 4 nt, XCD-bijective swizzle. LDS {A, B} 20KB dbuf.
// MODE 0: epilogue = +bias, relu, fp16 tiled write (feeds GEMM2).
// MODE 1: epilogue = +bias, relu, W3-slice dot (W3 in LDS) -> qpart[nt].
template<int NKT, int MODE>
__global__ __launch_bounds__(256, 4) void k_gemm(
    const f16* __restrict__ Ap, const f16* __restrict__ Bp,
    const float* __restrict__ bias, f16* __restrict__ C,
    const float* __restrict__ W3, float* __restrict__ qpart) {
    constexpr int SMEM = (MODE == 0) ? 20480 : 22528;
    __shared__ __align__(16) char smem[SMEM];
    f16* sA = (f16*)smem;                    // 2 bufs x 1024 f16 (4 KB)
    f16* sB = (f16*)(smem + 4096);           // 2 bufs x 4096 f16 (16 KB)
    int tid = threadIdx.x, wid = tid >> 6, lane = tid & 63;
    int id = blockIdx.x;
    int swz = (id & 7) * 200 + (id >> 3);    // bijective: 1600 % 8 == 0
    int nt = swz & 3, mt = swz >> 2;         // mt in [0,400)

    auto stage = [&](int kk, int buf) {
        #pragma unroll
        for (int j = 0; j < 3; ++j) {
            int seg = wid + 4 * j;           // 0..11
            if (seg < 2) {
                gload16(Ap + (size_t)(mt * NKT + kk) * 1024 + seg * 512 + lane * 8,
                        sA + buf * 1024 + seg * 512);
            } else if (seg < 10) {
                int s = seg - 2, q = s >> 2, kc = s & 3;
                gload16(Bp + ((size_t)((2 * nt + q) * NKT + kk) * 4 + kc) * 512 + lane * 8,
                        sB + buf * 4096 + (kc * 128 + q * 64) * 8);
            }
        }
    };

    int wr = wid >> 1, wc = wid & 1;         // wave-tile 16 rows x 64 cols
    int lrow = lane & 15, lk = lane >> 4;
    f32x4 acc[4] = {};

    stage(0, 0);
    for (int kk = 0; kk < NKT; ++kk) {
        int buf = kk & 1;
        __syncthreads();
        if (kk + 1 < NKT) stage(kk + 1, buf ^ 1);
        f16x8 a = *(const f16x8*)(sA + buf * 1024 + (lk * 32 + wr * 16 + lrow) * 8);
        f16x8 bh[4];
        #pragma unroll
        for (int j = 0; j < 4; ++j)
            bh[j] = *(const f16x8*)(sB + buf * 4096 + (lk * 128 + wc * 64 + j * 16 + lrow) * 8);
        #pragma unroll
        for (int j = 0; j < 4; ++j)
            acc[j] = __builtin_amdgcn_mfma_f32_16x16x32_f16(a, bh[j], acc[j], 0, 0, 0);
    }

    // transpose acc into sE[32][132] (staging dead after this barrier)
    __syncthreads();
    float* sE = (float*)smem;                // 32 x 132 fp32 = 16.9 KB
    #pragma unroll
    for (int j = 0; j < 4; ++j)
        #pragma unroll
        for (int r = 0; r < 4; ++r)
            sE[(wr * 16 + lk * 4 + r) * 132 + wc * 64 + j * 16 + lrow] = acc[j][r];

    if constexpr (MODE == 0) {
        __syncthreads();
        int l2 = tid & 31, og2 = tid >> 5;
        #pragma unroll
        for (int s2 = 0; s2 < 2; ++s2) {
            int o = og2 + 8 * s2;            // 0..15 local octet
            int n0 = nt * 128 + o * 8;
            f32x4 v0 = *(f32x4*)&sE[l2 * 132 + o * 8];
            f32x4 v1 = *(f32x4*)&sE[l2 * 132 + o * 8 + 4];
            f32x4 bb0 = *(const f32x4*)&bias[n0];
            f32x4 bb1 = *(const f32x4*)&bias[n0 + 4];
            f16 h8[8];
            #pragma unroll
            for (int i = 0; i < 4; ++i) {
                h8[i] = (f16)fmaxf(v0[i] + bb0[i], 0.f);
                h8[4 + i] = (f16)fmaxf(v1[i] + bb1[i], 0.f);
            }
            size_t off = ((size_t)mt * 64 + nt * 16 + o) * 256 + l2 * 8;
            *(f16x8*)&C[off] = *(f16x8*)h8;
        }
    } else {
        // stage W3 slice (128 x 11 = 5.6 KB) into LDS, coalesced
        float* W3s = (float*)(smem + 16896);
        for (int i = tid; i < 128 * NOUT; i += 256)
            W3s[i] = W3[nt * 128 * NOUT + i];
        __syncthreads();
        int row = tid >> 3, seg = tid & 7;   // 8 threads per row
        float a11[NOUT];
        #pragma unroll
        for (int n = 0; n < NOUT; ++n) a11[n] = 0.f;
        #pragma unroll
        for (int c16 = 0; c16 < 16; ++c16) {
            int col = seg + 8 * c16;         // stride-8: <=2-way LDS conflict
            float h = fmaxf(sE[row * 132 + col] + bias[nt * 128 + col], 0.f);
            const float* w = W3s + col * NOUT;
            #pragma unroll
            for (int n = 0; n < NOUT; ++n) a11[n] += h * w[n];
        }
        #pragma unroll
        for (int d = 4; d >= 1; d >>= 1)
            #pragma unroll
            for (int n = 0; n < NOUT; ++n) a11[n] += __shfl_down(a11[n], d, 64);
        if (seg == 0) {
            int grow = mt * 32 + row;
            #pragma unroll
            for (int n = 0; n < NOUT; ++n)
                qpart[(size_t)nt * NROWS * NOUT + (size_t)grow * NOUT + n] = a11[n];
        }
    }
}

// ---------------- reduce 4 q-partials + b3 ----------------
__global__ __launch_bounds__(256) void k_qreduce(const float* __restrict__ qp,
                                                 const float* __restrict__ b3,
                                                 float* __restrict__ out) {
    int i = blockIdx.x * 256 + threadIdx.x;
    if (i < NROWS * NOUT) {
        int n = i % NOUT;
        const size_t P = (size_t)NROWS * NOUT;
        out[i] = b3[n] + qp[i] + qp[i + P] + qp[i + 2 * P] + qp[i + 3 * P];
    }
}

extern "C" void kernel_launch(void* const* d_in, const int* in_sizes, int n_in,
                              void* d_out, int out_size, void* d_ws, size_t ws_size,
                              hipStream_t stream) {
    const float* beta    = (const float*)d_in[0];
    const float* actions = (const float*)d_in[1];
    const float* power   = (const float*)d_in[2];
    const int*   prev    = (const int*)d_in[3];
    const float* W1      = (const float*)d_in[4];
    const float* b1      = (const float*)d_in[5];
    const float* W2      = (const float*)d_in[6];
    const float* b2      = (const float*)d_in[7];
    const float* W3      = (const float*)d_in[8];
    const float* b3      = (const float*)d_in[9];
    float* out = (float*)d_out;

    char* ws = (char*)d_ws;
    size_t off = 0;
    auto alloc = [&](size_t bytes) { void* p = ws + off; off += (bytes + 255) & ~(size_t)255; return p; };
    float* total_beta = (float*)alloc((size_t)NROWS * MTASK * 4);
    int*   tasks      = (int*)  alloc((size_t)NROWS * MTOP * 4);
    int*   neighbors  = (int*)  alloc((size_t)NROWS * NNB * 4);
    f16*   A    = (f16*)alloc((size_t)NROWS * KP1 * 2);
    f16*   W1t  = (f16*)alloc((size_t)HDIM * KP1 * 2);
    f16*   W2t  = (f16*)alloc((size_t)HDIM * HDIM * 2);
    f16*   h1   = (f16*)alloc((size_t)NROWS * HDIM * 2);
    float* qpart = (float*)alloc((size_t)4 * NROWS * NOUT * 4);

    k_topk<<<NROWS / 4, 256, 0, stream>>>(beta, total_beta, tasks);
    k_nbrs<<<NROWS / 4, 256, 0, stream>>>(total_beta, tasks, neighbors);
    k_build_inputs<<<NROWS / 8, 256, 0, stream>>>(beta, actions, power, prev, tasks,
                                                  neighbors, A);
    {
        dim3 gp(KP1 / 64 + HDIM / 64, HDIM / 64);
        k_prep_wt<<<gp, 256, 0, stream>>>(W1, W2, W1t, W2t);
    }
    // GEMM1: fused b1+relu epilogue -> h1 (fp16 tiled)
    k_gemm<NKT1, 0><<<1600, 256, 0, stream>>>(A, W1t, b1, h1, nullptr, nullptr);
    // GEMM2: fused b2+relu+W3-slice dot -> qpart
    k_gemm<NKT2, 1><<<1600, 256, 0, stream>>>(h1, W2t, b2, nullptr, W3, qpart);
    k_qreduce<<<(NROWS * NOUT + 255) / 256, 256, 0, stream>>>(qpart, b3, out);
}